// Round 1
// baseline (3089.650 us; speedup 1.0000x reference)
//
#include <hip/hip_runtime.h>

typedef unsigned short u16t;
typedef __bf16 bf16x8 __attribute__((ext_vector_type(8)));
typedef float floatx4 __attribute__((ext_vector_type(4)));
typedef u16t u16x8 __attribute__((ext_vector_type(8)));
typedef u16t u16x4 __attribute__((ext_vector_type(4)));

#define EPSF 1e-15f

__device__ __forceinline__ u16t f2bf(float f){
  unsigned u = __float_as_uint(f);
  u += 0x7fffu + ((u >> 16) & 1u);
  return (u16t)(u >> 16);
}
__device__ __forceinline__ float bf2f(u16t h){
  return __uint_as_float(((unsigned)h) << 16);
}

__device__ __forceinline__ float waveSum(float v){
  #pragma unroll
  for (int o = 32; o > 0; o >>= 1) v += __shfl_xor(v, o, 64);
  return v;
}
__device__ __forceinline__ float waveMax(float v){
  #pragma unroll
  for (int o = 32; o > 0; o >>= 1) v = fmaxf(v, __shfl_xor(v, o, 64));
  return v;
}
__device__ __forceinline__ float blockSum(float v, float* red){
  int lane = threadIdx.x & 63, w = threadIdx.x >> 6;
  v = waveSum(v);
  __syncthreads();
  if (lane == 0) red[w] = v;
  __syncthreads();
  float tot = 0.f;
  int nw = blockDim.x >> 6;
  for (int i = 0; i < nw; i++) tot += red[i];
  return tot;
}

// ---------------------------------------------------------------------------
// Generic 128x128x32 bf16 MFMA GEMM. A: fp32 (converted on the fly) or bf16.
// B: bf16, staged transposed into LDS so the hot loop is ds_read_b128 only.
// EPI: 0 = fp32 out (+bias), 1 = relu(acc+bias)*mask[row] -> bf16,
//      2 = bf16 out, 3 = fp32 out = acc + bf16 addsrc[row,col] + bias[col].
// DFLAT: also emit row-sums of A (valid when gridDim.x == 1).
// ---------------------------------------------------------------------------
template<bool AF32, int EPI, bool DFLAT>
__global__ __launch_bounds__(256) void gemm_k(
    const void* __restrict__ Aptr, const u16t* __restrict__ Bptr, void* __restrict__ Cptr,
    int M, int N, int K, int lda, int ldb, int ldc,
    long long sA, long long sB, long long sC,
    const float* __restrict__ bias, int biasmax,
    const u16t* __restrict__ addsrc, int ldadd, long long sAdd,
    const float* __restrict__ mask,
    float* __restrict__ dflat, long long sD)
{
  __shared__ u16t As[128 * 40];
  __shared__ u16t Bs[128 * 40];
  const int bz = blockIdx.z;
  const int bm0 = blockIdx.y * 128, bn0 = blockIdx.x * 128;
  const int t = threadIdx.x;
  const int lane = t & 63, wid = t >> 6;
  const int wm = wid >> 1, wn = wid & 1;
  const int l16 = lane & 15, quad = lane >> 4;

  const float* Af = (const float*)Aptr + (AF32 ? (size_t)(bz * sA) : 0);
  const u16t*  Ah = (const u16t*)Aptr + (AF32 ? 0 : (size_t)(bz * sA));
  const u16t*  B  = Bptr + (size_t)(bz * sB);

  floatx4 acc[4][4];
  #pragma unroll
  for (int i = 0; i < 4; i++)
    #pragma unroll
    for (int j = 0; j < 4; j++)
      #pragma unroll
      for (int rg = 0; rg < 4; rg++) acc[i][j][rg] = 0.f;

  float dsum = 0.f;

  for (int k0 = 0; k0 < K; k0 += 32){
    __syncthreads();
    if constexpr (AF32){
      #pragma unroll
      for (int i = 0; i < 4; i++){
        int c = t + i * 256;
        int r = c >> 3, c4 = c & 7;
        int gr = bm0 + r;
        float4 v = make_float4(0.f, 0.f, 0.f, 0.f);
        if (gr < M) v = *(const float4*)(Af + (size_t)gr * lda + k0 + c4 * 4);
        u16x4 hv;
        hv[0] = f2bf(v.x); hv[1] = f2bf(v.y); hv[2] = f2bf(v.z); hv[3] = f2bf(v.w);
        *(u16x4*)(&As[r * 40 + c4 * 4]) = hv;
      }
    } else {
      #pragma unroll
      for (int i = 0; i < 2; i++){
        int c = t + i * 256;
        int r = c >> 2, c8 = c & 3;
        int gr = bm0 + r;
        u16x8 v = {0,0,0,0,0,0,0,0};
        if (gr < M) v = *(const u16x8*)(Ah + (size_t)gr * lda + k0 + c8 * 8);
        *(u16x8*)(&As[r * 40 + c8 * 8]) = v;
      }
    }
    // B staged transposed: Bs[n][k], per-thread gather of 8 k's for one column.
    #pragma unroll
    for (int i = 0; i < 2; i++){
      int c = t + i * 256;
      int n = c & 127, kg = c >> 7;
      int gc = bn0 + n;
      u16x8 v = {0,0,0,0,0,0,0,0};
      if (gc < N){
        #pragma unroll
        for (int j = 0; j < 8; j++)
          v[j] = B[(size_t)(k0 + kg * 8 + j) * ldb + gc];
      }
      *(u16x8*)(&Bs[n * 40 + kg * 8]) = v;
    }
    __syncthreads();
    if constexpr (DFLAT){
      int r = t >> 1, half = t & 1;
      float s = 0.f;
      #pragma unroll
      for (int q = 0; q < 16; q++) s += bf2f(As[r * 40 + half * 16 + q]);
      dsum += s;
    }
    u16x8 a[4], b[4];
    #pragma unroll
    for (int i = 0; i < 4; i++) a[i] = *(const u16x8*)(&As[(wm * 64 + i * 16 + l16) * 40 + quad * 8]);
    #pragma unroll
    for (int j = 0; j < 4; j++) b[j] = *(const u16x8*)(&Bs[(wn * 64 + j * 16 + l16) * 40 + quad * 8]);
    #pragma unroll
    for (int i = 0; i < 4; i++)
      #pragma unroll
      for (int j = 0; j < 4; j++)
        acc[i][j] = __builtin_amdgcn_mfma_f32_16x16x32_bf16(
            __builtin_bit_cast(bf16x8, a[i]), __builtin_bit_cast(bf16x8, b[j]),
            acc[i][j], 0, 0, 0);
  }

  if constexpr (DFLAT){
    float other = __shfl_xor(dsum, 1, 64);
    if ((t & 1) == 0){
      int gr = bm0 + (t >> 1);
      if (gr < M) dflat[(size_t)(bz * sD) + gr] = dsum + other;
    }
  }

  float* Cf = (float*)Cptr + (size_t)(bz * sC);
  u16t*  Ch = (u16t*)Cptr + (size_t)(bz * sC);
  const u16t* addp = (EPI == 3) ? (addsrc + (size_t)(bz * sAdd)) : nullptr;
  #pragma unroll
  for (int i = 0; i < 4; i++){
    int rb = bm0 + wm * 64 + i * 16 + quad * 4;
    #pragma unroll
    for (int j = 0; j < 4; j++){
      int col = bn0 + wn * 64 + j * 16 + l16;
      if (col >= N) continue;
      float bv = bias ? bias[col > biasmax ? biasmax : col] : 0.f;
      #pragma unroll
      for (int rg = 0; rg < 4; rg++){
        int row = rb + rg;
        if (row >= M) continue;
        float v = acc[i][j][rg] + bv;
        if constexpr (EPI == 1){
          v = fmaxf(v, 0.f) * mask[row];
          Ch[(size_t)row * ldc + col] = f2bf(v);
        } else if constexpr (EPI == 2){
          Ch[(size_t)row * ldc + col] = f2bf(v);
        } else if constexpr (EPI == 3){
          v += bf2f(addp[(size_t)row * ldadd + col]);
          Cf[(size_t)row * ldc + col] = v;
        } else {
          Cf[(size_t)row * ldc + col] = v;
        }
      }
    }
  }
}

// --------------------------------------------------------------------------
__global__ void init_k(float* scal){ if (threadIdx.x < 8) scal[threadIdx.x] = 0.f; }

__global__ void cvt_k(const float* __restrict__ s, u16t* __restrict__ d, int n){
  int i = blockIdx.x * 256 + threadIdx.x;
  if (i < n) d[i] = f2bf(s[i]);
}

// L2-normalize rows of Z [16384][512] -> bf16 into CC[:, 0:512] (ld 768)
__global__ __launch_bounds__(256) void norm_k(const float* __restrict__ Z, u16t* __restrict__ CC){
  __shared__ float red[8];
  int n = blockIdx.x, t = threadIdx.x;
  const float* z = Z + (size_t)n * 512;
  float v0 = z[t], v1 = z[t + 256];
  float tot = blockSum(v0 * v0 + v1 * v1, red);
  float inv = 1.f / (sqrtf(tot) + 1e-12f);
  u16t* o = CC + (size_t)n * 768;
  o[t] = f2bf(v0 * inv);
  o[t + 256] = f2bf(v1 * inv);
}

// softmax over 100 cols; write s (bf16) into CC[:,624:724] and s^T into ST
__global__ __launch_bounds__(256) void softmax_k(const float* __restrict__ SR, const float* __restrict__ mask,
                                                 u16t* __restrict__ CC, u16t* __restrict__ ST){
  int w = threadIdx.x >> 6, lane = threadIdx.x & 63;
  int n = blockIdx.x * 4 + w;
  const float* r = SR + (size_t)n * 112;
  float v0 = (lane < 100) ? r[lane] : -1e30f;
  float v1 = (lane + 64 < 100) ? r[lane + 64] : -1e30f;
  float m = waveMax(fmaxf(v0, v1));
  float e0 = (lane < 100) ? __expf(v0 - m) : 0.f;
  float e1 = (lane + 64 < 100) ? __expf(v1 - m) : 0.f;
  float s = waveSum(e0 + e1);
  float inv = mask[n] / s;
  int b = n >> 13, nn = n & 8191;
  u16t* cc = CC + (size_t)n * 768 + 624;
  if (lane < 100){
    u16t h = f2bf(e0 * inv);
    cc[lane] = h;
    ST[((size_t)b * 112 + lane) * 8192 + nn] = h;
  }
  if (lane + 64 < 100){
    u16t h = f2bf(e1 * inv);
    cc[lane + 64] = h;
    ST[((size_t)b * 112 + lane + 64) * 8192 + nn] = h;
  }
}

// mincut_den[b] = sum_n dflat[n] * sum_k s[n,k]^2
__global__ __launch_bounds__(256) void den_k(const u16t* __restrict__ CC, const float* __restrict__ dflat,
                                             float* __restrict__ scal){
  __shared__ float red[8];
  int n = blockIdx.x * 256 + threadIdx.x;
  const u16t* s = CC + (size_t)n * 768 + 624;
  float ssq = 0.f;
  for (int k = 0; k < 100; k++){ float v = bf2f(s[k]); ssq += v * v; }
  float tot = blockSum(dflat[n] * ssq, red);
  if (threadIdx.x == 0) atomicAdd(&scal[n >> 13], tot);
}

// loss scalar: mincut (trace from OUT diag / den) + ortho (from ss block)
__global__ __launch_bounds__(256) void losses_k(const float* __restrict__ OUTB, const float* __restrict__ scal,
                                                float* __restrict__ dout){
  __shared__ float red[8];
  __shared__ float fro[2], orth[2], num[2];
  int t = threadIdx.x;
  for (int b = 0; b < 2; b++){
    const float* base = OUTB + (size_t)b * 112 * 768;
    float p = 0.f;
    for (int idx = t; idx < 10000; idx += 256){
      int k = idx / 100, l = idx - k * 100;
      float v = base[(size_t)k * 768 + 624 + l];
      p += v * v;
    }
    float tot = blockSum(p, red);
    if (t == 0) fro[b] = sqrtf(tot);
    float q = (t < 100) ? base[(size_t)t * 768 + 512 + t] : 0.f;
    float ntot = blockSum(q, red);
    if (t == 0) num[b] = ntot;
  }
  __syncthreads();
  for (int b = 0; b < 2; b++){
    const float* base = OUTB + (size_t)b * 112 * 768;
    float f = fro[b] + EPSF;
    float p = 0.f;
    for (int idx = t; idx < 10000; idx += 256){
      int k = idx / 100, l = idx - k * 100;
      float v = base[(size_t)k * 768 + 624 + l] / f - ((k == l) ? 0.1f : 0.f);
      p += v * v;
    }
    float tot = blockSum(p, red);
    if (t == 0) orth[b] = sqrtf(tot);
  }
  __syncthreads();
  if (t == 0){
    float mc = -0.5f * (num[0] / (scal[0] + EPSF) + num[1] / (scal[1] + EPSF));
    float ol = 0.5f * (orth[0] + orth[1]);
    dout[404] = mc + ol;
  }
}

// out_adj: zero diag, symmetric degree normalize, write to d_out
__global__ __launch_bounds__(256) void outadj_k(const float* __restrict__ OUTB, float* __restrict__ dout){
  __shared__ float T[10000];
  __shared__ float D[100];
  int b = blockIdx.x, t = threadIdx.x;
  const float* base = OUTB + (size_t)b * 112 * 768;
  for (int idx = t; idx < 10000; idx += 256){
    int k = idx / 100, l = idx - k * 100;
    T[idx] = (k == l) ? 0.f : base[(size_t)k * 768 + 512 + l];
  }
  __syncthreads();
  if (t < 100){
    float s = 0.f;
    for (int l = 0; l < 100; l++) s += T[t * 100 + l];
    D[t] = sqrtf(s) + EPSF;
  }
  __syncthreads();
  float* o = dout + 33173 + b * 10000;
  for (int idx = t; idx < 10000; idx += 256){
    int k = idx / 100, l = idx - k * 100;
    o[idx] = T[idx] / (D[k] * D[l]);
  }
}

// Xp = [cls; out rows]; attn = sigmoid(tanh(Xp@aw1+ab1)@aw2+ab2); wil = attn*(Xp@pred_w+pred_b)
__global__ __launch_bounds__(256) void attn_k(const float* __restrict__ OUTB, const float* __restrict__ cls,
    const float* __restrict__ aw1, const float* __restrict__ ab1,
    const float* __restrict__ aw2, const float* __restrict__ ab2,
    const float* __restrict__ pw, const float* __restrict__ pb, float* __restrict__ dout){
  __shared__ float xp[512];
  __shared__ float h[512];
  __shared__ float red[8];
  int blk = blockIdx.x;
  int b = blk / 101, r = blk % 101;
  int t = threadIdx.x;
  const float* src = (r == 0) ? cls : (OUTB + ((size_t)b * 112 + (r - 1)) * 768);
  xp[t] = src[t]; xp[t + 256] = src[t + 256];
  __syncthreads();
  #pragma unroll
  for (int ee = 0; ee < 2; ee++){
    int e = t + ee * 256;
    float acc = ab1[e];
    for (int f = 0; f < 512; f++) acc += xp[f] * aw1[(size_t)f * 512 + e];
    h[e] = tanhf(acc);
  }
  __syncthreads();
  float pa = h[t] * aw2[t] + h[t + 256] * aw2[t + 256];
  float alog = blockSum(pa, red);
  float attn = 1.f / (1.f + __expf(-(alog + ab2[0])));
  float p0 = xp[t] * pw[(size_t)t * 2] + xp[t + 256] * pw[(size_t)(t + 256) * 2];
  float l0 = blockSum(p0, red);
  float p1 = xp[t] * pw[(size_t)t * 2 + 1] + xp[t + 256] * pw[(size_t)(t + 256) * 2 + 1];
  float l1 = blockSum(p1, red);
  if (t == 0){
    dout[((size_t)b * 101 + r) * 2 + 0] = attn * (l0 + pb[0]);
    dout[((size_t)b * 101 + r) * 2 + 1] = attn * (l1 + pb[1]);
  }
}

// CrossGatingFusion: gates + merge + layernorm, one block per proto row
__global__ __launch_bounds__(256) void fusion_k(const float* __restrict__ PL, const float* __restrict__ PR,
    const float* __restrict__ GLW, const float* __restrict__ GLB,
    const float* __restrict__ GRW, const float* __restrict__ GRB,
    const float* __restrict__ LG, const float* __restrict__ LB, float* __restrict__ dout){
  __shared__ float pl[1024], pr[1024], pre[1024];
  __shared__ float red[8];
  int p = blockIdx.x, t = threadIdx.x;
  #pragma unroll
  for (int i = 0; i < 4; i++){
    pl[t + i * 256] = PL[(size_t)p * 1024 + t + i * 256];
    pr[t + i * 256] = PR[(size_t)p * 1024 + t + i * 256];
  }
  __syncthreads();
  #pragma unroll
  for (int i = 0; i < 4; i++){
    int j = t + i * 256;
    float al = GLB[j], ar = GRB[j];
    for (int d = 0; d < 1024; d++){
      al += pl[d] * GLW[(size_t)d * 1024 + j];
      ar += pr[d] * GRW[(size_t)d * 1024 + j];
    }
    float gl = 1.f / (1.f + __expf(-al));
    float gr = 1.f / (1.f + __expf(-ar));
    pre[j] = gl * pl[j] + gr * pr[j];
  }
  __syncthreads();
  float ps = 0.f;
  for (int i = 0; i < 4; i++) ps += pre[t + i * 256];
  float mu = blockSum(ps, red) * (1.f / 1024.f);
  float pv = 0.f;
  for (int i = 0; i < 4; i++){ float d = pre[t + i * 256] - mu; pv += d * d; }
  float var = blockSum(pv, red) * (1.f / 1024.f);
  float rs = rsqrtf(var + 1e-5f);
  float* o = dout + 405 + (size_t)p * 1024;
  for (int i = 0; i < 4; i++){
    int j = t + i * 256;
    o[j] = (pre[j] - mu) * rs * LG[j] + LB[j];
  }
}

// ===========================================================================
extern "C" void kernel_launch(void* const* d_in, const int* in_sizes, int n_in,
                              void* d_out, int out_size, void* d_ws, size_t ws_size,
                              hipStream_t stream)
{
  const float* node_feat = (const float*)d_in[0];
  const float* adj   = (const float*)d_in[1];
  const float* maskp = (const float*)d_in[2];
  const float* fc1w  = (const float*)d_in[3];
  const float* fc1b  = (const float*)d_in[4];
  const float* gcnw  = (const float*)d_in[5];
  const float* gcnb  = (const float*)d_in[6];
  const float* poolw = (const float*)d_in[7];
  const float* poolb = (const float*)d_in[8];
  const float* cls   = (const float*)d_in[9];
  const float* aw1   = (const float*)d_in[10];
  const float* ab1   = (const float*)d_in[11];
  const float* aw2   = (const float*)d_in[12];
  const float* ab2   = (const float*)d_in[13];
  const float* predw = (const float*)d_in[14];
  const float* predb = (const float*)d_in[15];
  const float* glw   = (const float*)d_in[16];
  const float* glb   = (const float*)d_in[17];
  const float* grw   = (const float*)d_in[18];
  const float* grb   = (const float*)d_in[19];
  const float* lng   = (const float*)d_in[20];
  const float* lnb   = (const float*)d_in[21];
  const float* prl   = (const float*)d_in[22];
  const float* prr   = (const float*)d_in[23];
  float* dout = (float*)d_out;

  char* ws = (char*)d_ws;
  size_t off = 0;
  auto take = [&](size_t bytes) -> char* {
    char* p = ws + off;
    off = (off + bytes + 255) & ~(size_t)255;
    return p;
  };
  u16t* FC1W  = (u16t*)take((size_t)1024 * 512 * 2);
  u16t* GCNW  = (u16t*)take((size_t)512 * 512 * 2);
  u16t* POOLW = (u16t*)take((size_t)512 * 100 * 2);
  u16t* X1    = (u16t*)take((size_t)16384 * 512 * 2);
  u16t* W     = (u16t*)take((size_t)16384 * 512 * 2);
  float* Z    = (float*)take((size_t)16384 * 512 * 4);
  u16t* CC    = (u16t*)take((size_t)2 * 8192 * 768 * 2);  // [X2 | Y3 | s] per row
  u16t* ST    = (u16t*)take((size_t)2 * 112 * 8192 * 2);  // s^T
  float* OUTB = (float*)take((size_t)2 * 112 * 768 * 4);  // [out | s^T A s | s^T s]
  float* DFLAT= (float*)take((size_t)16384 * 4);
  float* SCAL = (float*)take(256);
  float* SRAW = (float*)X1;  // X1 is dead once W is built; reuse for s_raw

  init_k<<<1, 64, 0, stream>>>(SCAL);
  cvt_k<<<(1024 * 512 + 255) / 256, 256, 0, stream>>>(fc1w, FC1W, 1024 * 512);
  cvt_k<<<(512 * 512 + 255) / 256, 256, 0, stream>>>(gcnw, GCNW, 512 * 512);
  cvt_k<<<(512 * 100 + 255) / 256, 256, 0, stream>>>(poolw, POOLW, 512 * 100);

  // X1 = relu(node_feat @ fc1_w + fc1_b) * mask   [16384, 512] bf16
  gemm_k<true, 1, false><<<dim3(4, 128, 1), 256, 0, stream>>>(
      node_feat, FC1W, X1, 16384, 512, 1024, 1024, 512, 512,
      0, 0, 0, fc1b, 511, nullptr, 0, 0, maskp, nullptr, 0);
  // W = X1 @ gcn_w   [16384, 512] bf16
  gemm_k<false, 2, false><<<dim3(4, 128, 1), 256, 0, stream>>>(
      X1, GCNW, W, 16384, 512, 512, 512, 512, 512,
      0, 0, 0, nullptr, 0, nullptr, 0, 0, nullptr, nullptr, 0);
  // Z = adj @ W + W + gcn_b   (per batch)  [16384, 512] fp32
  gemm_k<true, 3, false><<<dim3(4, 64, 2), 256, 0, stream>>>(
      adj, W, Z, 8192, 512, 8192, 8192, 512, 512,
      (long long)8192 * 8192, (long long)8192 * 512, (long long)8192 * 512,
      gcnb, 511, W, 512, (long long)8192 * 512, nullptr, nullptr, 0);
  // X2 = row-normalize(Z) -> CC[:, 0:512]
  norm_k<<<16384, 256, 0, stream>>>(Z, CC);
  // s_raw = X2 @ pool_w + pool_b  [16384, 100] fp32 (ld 112)
  gemm_k<false, 0, false><<<dim3(1, 128, 1), 256, 0, stream>>>(
      CC, POOLW, SRAW, 16384, 100, 512, 768, 100, 112,
      0, 0, 0, poolb, 99, nullptr, 0, 0, nullptr, nullptr, 0);
  // s = softmax(s_raw) * mask -> CC[:, 624:724] and ST
  softmax_k<<<4096, 256, 0, stream>>>(SRAW, maskp, CC, ST);
  // Y3 = adj @ s -> CC[:, 512:612]; also d_flat = adj.sum(-1)
  gemm_k<true, 2, true><<<dim3(1, 64, 2), 256, 0, stream>>>(
      adj, CC + 624, (void*)(CC + 512), 8192, 100, 8192, 8192, 768, 768,
      (long long)8192 * 8192, (long long)8192 * 768, (long long)8192 * 768,
      nullptr, 0, nullptr, 0, 0, nullptr, DFLAT, 8192);
  // OUTB = s^T @ [X2 | Y3 | s]  -> [out | s^T A s | s^T s]  (per batch)
  gemm_k<false, 0, false><<<dim3(6, 1, 2), 256, 0, stream>>>(
      ST, CC, OUTB, 100, 736, 8192, 8192, 768, 768,
      (long long)112 * 8192, (long long)8192 * 768, (long long)112 * 768,
      nullptr, 0, nullptr, 0, 0, nullptr, nullptr, 0);

  den_k<<<64, 256, 0, stream>>>(CC, DFLAT, SCAL);
  losses_k<<<1, 256, 0, stream>>>(OUTB, SCAL, dout);
  outadj_k<<<2, 256, 0, stream>>>(OUTB, dout);
  attn_k<<<202, 256, 0, stream>>>(OUTB, cls, aw1, ab1, aw2, ab2, predw, predb, dout);
  fusion_k<<<32, 256, 0, stream>>>(prl, prr, glw, glb, grw, grb, lng, lnb, dout);

  (void)in_sizes; (void)n_in; (void)out_size; (void)ws_size;
}

// Round 2
// 1796.707 us; speedup vs baseline: 1.7196x; 1.7196x over previous
//
#include <hip/hip_runtime.h>

typedef unsigned short u16t;
typedef __bf16 bf16x8 __attribute__((ext_vector_type(8)));
typedef float floatx4 __attribute__((ext_vector_type(4)));
typedef u16t u16x8 __attribute__((ext_vector_type(8)));
typedef u16t u16x4 __attribute__((ext_vector_type(4)));

#define EPSF 1e-15f

__device__ __forceinline__ u16t f2bf(float f){
  unsigned u = __float_as_uint(f);
  u += 0x7fffu + ((u >> 16) & 1u);
  return (u16t)(u >> 16);
}
__device__ __forceinline__ float bf2f(u16t h){
  return __uint_as_float(((unsigned)h) << 16);
}

__device__ __forceinline__ float waveSum(float v){
  #pragma unroll
  for (int o = 32; o > 0; o >>= 1) v += __shfl_xor(v, o, 64);
  return v;
}
__device__ __forceinline__ float waveMax(float v){
  #pragma unroll
  for (int o = 32; o > 0; o >>= 1) v = fmaxf(v, __shfl_xor(v, o, 64));
  return v;
}
__device__ __forceinline__ float blockSum(float v, float* red){
  int lane = threadIdx.x & 63, w = threadIdx.x >> 6;
  v = waveSum(v);
  __syncthreads();
  if (lane == 0) red[w] = v;
  __syncthreads();
  float tot = 0.f;
  int nw = blockDim.x >> 6;
  for (int i = 0; i < nw; i++) tot += red[i];
  return tot;
}

// ---------------------------------------------------------------------------
// Transpose + cvt: src [M x N] (fp32 or bf16) -> dst bf16 [N x M]. 64x64 tiles.
// ---------------------------------------------------------------------------
template<bool SRCF32>
__global__ __launch_bounds__(256) void tr_k(const void* __restrict__ S, u16t* __restrict__ D,
    int M, int N, int lds_, int ldd, long long sS, long long sD)
{
  __shared__ u16t T[64][72];
  const int bz = blockIdx.z;
  const int r0 = blockIdx.y * 64, c0 = blockIdx.x * 64;
  const int t = threadIdx.x;
  const float* Sf = (const float*)S + (SRCF32 ? (size_t)bz * sS : 0);
  const u16t*  Sh = (const u16t*)S + (SRCF32 ? 0 : (size_t)bz * sS);
  #pragma unroll
  for (int p = 0; p < 2; p++){
    int row = p * 32 + (t >> 3), c8 = t & 7;
    int gr = r0 + row, gc = c0 + c8 * 8;
    u16x8 v = {0,0,0,0,0,0,0,0};
    if (gr < M){
      if constexpr (SRCF32){
        #pragma unroll
        for (int j = 0; j < 8; j++){
          int cc = gc + j;
          if (cc < N) v[j] = f2bf(Sf[(size_t)gr * lds_ + cc]);
        }
      } else {
        if (gc + 7 < N) v = *(const u16x8*)(Sh + (size_t)gr * lds_ + gc);
        else {
          #pragma unroll
          for (int j = 0; j < 8; j++){ int cc = gc + j; if (cc < N) v[j] = Sh[(size_t)gr * lds_ + cc]; }
        }
      }
    }
    *(u16x8*)(&T[row][c8 * 8]) = v;
  }
  __syncthreads();
  u16t* Db = D + (size_t)bz * sD;
  #pragma unroll
  for (int p = 0; p < 2; p++){
    int orow = p * 32 + (t >> 3), o8 = t & 7;
    int gc = c0 + orow;        // dst row (src col)
    int gr = r0 + o8 * 8;      // dst col base (src row)
    if (gc < N){
      u16x8 v;
      #pragma unroll
      for (int j = 0; j < 8; j++) v[j] = T[o8 * 8 + j][orow];
      if (gr + 7 < M) *(u16x8*)(Db + (size_t)gc * ldd + gr) = v;
      else {
        #pragma unroll
        for (int j = 0; j < 8; j++) if (gr + j < M) Db[(size_t)gc * ldd + gr + j] = v[j];
      }
    }
  }
}

// ---------------------------------------------------------------------------
// 128x128x32 bf16 MFMA GEMM; B pre-transposed [N x K] row-major -> both tiles
// staged with vectorized loads. Register-prefetch double buffering.
// EPI: 0 fp32 (+bias), 1 relu(acc+bias)*mask -> bf16, 2 bf16,
//      3 fp32 = acc + bf16 addsrc + bias, 4 atomicAdd fp32 (split-K).
// blockIdx.x = kChunk * nbx + nBlock.
// ---------------------------------------------------------------------------
template<bool AF32, int EPI, bool DFLAT>
__global__ __launch_bounds__(256) void gemm_k(
    const void* __restrict__ Aptr, const u16t* __restrict__ Bt, void* __restrict__ Cptr,
    int M, int N, int K, int lda, int ldbt, int ldc,
    long long sA, long long sB, long long sC,
    const float* __restrict__ bias, int biasmax,
    const u16t* __restrict__ addsrc, int ldadd, long long sAdd,
    const float* __restrict__ mask,
    float* __restrict__ dflat,
    int nbx, int klen)
{
  __shared__ u16t As[128 * 40];
  __shared__ u16t Bs[128 * 40];
  const int bz = blockIdx.z;
  const int kc = blockIdx.x / nbx;
  const int bn0 = (blockIdx.x % nbx) * 128;
  const int bm0 = blockIdx.y * 128;
  const int t = threadIdx.x;
  const int lane = t & 63, wid = t >> 6;
  const int wm = wid >> 1, wn = wid & 1;
  const int l16 = lane & 15, quad = lane >> 4;
  const int kBeg = kc * klen;
  const int kEnd = (kBeg + klen < K) ? (kBeg + klen) : K;

  const float* Af = (const float*)Aptr + (AF32 ? (size_t)(bz * sA) : 0);
  const u16t*  Ah = (const u16t*)Aptr + (AF32 ? 0 : (size_t)(bz * sA));
  const u16t*  Bp = Bt + (size_t)(bz * sB);

  floatx4 acc[4][4];
  #pragma unroll
  for (int i = 0; i < 4; i++)
    #pragma unroll
    for (int j = 0; j < 4; j++)
      #pragma unroll
      for (int rg = 0; rg < 4; rg++) acc[i][j][rg] = 0.f;

  float dsum = 0.f;

  float4 afv[4];
  u16x8 ahv[2];
  u16x8 bhv[2];

  auto loadA = [&](int k0){
    if constexpr (AF32){
      #pragma unroll
      for (int i = 0; i < 4; i++){
        int c = t + i * 256;
        int r = c >> 3, c4 = c & 7;
        int gr = bm0 + r;
        afv[i] = make_float4(0.f, 0.f, 0.f, 0.f);
        if (gr < M) afv[i] = *(const float4*)(Af + (size_t)gr * lda + k0 + c4 * 4);
      }
    } else {
      #pragma unroll
      for (int i = 0; i < 2; i++){
        int c = t + i * 256;
        int r = c >> 2, c8 = c & 3;
        int gr = bm0 + r;
        ahv[i] = (u16x8){0,0,0,0,0,0,0,0};
        if (gr < M) ahv[i] = *(const u16x8*)(Ah + (size_t)gr * lda + k0 + c8 * 8);
      }
    }
  };
  auto loadB = [&](int k0){
    #pragma unroll
    for (int i = 0; i < 2; i++){
      int c = t + i * 256;
      int n = c >> 2, c8 = c & 3;
      int gc = bn0 + n;
      bhv[i] = (u16x8){0,0,0,0,0,0,0,0};
      if (gc < N) bhv[i] = *(const u16x8*)(Bp + (size_t)gc * ldbt + k0 + c8 * 8);
    }
  };
  auto storeTiles = [&](){
    if constexpr (AF32){
      #pragma unroll
      for (int i = 0; i < 4; i++){
        int c = t + i * 256;
        int r = c >> 3, c4 = c & 7;
        u16x4 hv;
        hv[0] = f2bf(afv[i].x); hv[1] = f2bf(afv[i].y);
        hv[2] = f2bf(afv[i].z); hv[3] = f2bf(afv[i].w);
        *(u16x4*)(&As[r * 40 + c4 * 4]) = hv;
      }
    } else {
      #pragma unroll
      for (int i = 0; i < 2; i++){
        int c = t + i * 256;
        int r = c >> 2, c8 = c & 3;
        *(u16x8*)(&As[r * 40 + c8 * 8]) = ahv[i];
      }
    }
    #pragma unroll
    for (int i = 0; i < 2; i++){
      int c = t + i * 256;
      int n = c >> 2, c8 = c & 3;
      *(u16x8*)(&Bs[n * 40 + c8 * 8]) = bhv[i];
    }
  };

  loadA(kBeg); loadB(kBeg);

  for (int k0 = kBeg; k0 < kEnd; k0 += 32){
    __syncthreads();
    storeTiles();
    __syncthreads();
    if (k0 + 32 < kEnd){ loadA(k0 + 32); loadB(k0 + 32); }
    if constexpr (DFLAT){
      int r = t >> 1, half = t & 1;
      float s = 0.f;
      #pragma unroll
      for (int q = 0; q < 16; q++) s += bf2f(As[r * 40 + half * 16 + q]);
      dsum += s;
    }
    u16x8 a[4], b[4];
    #pragma unroll
    for (int i = 0; i < 4; i++) a[i] = *(const u16x8*)(&As[(wm * 64 + i * 16 + l16) * 40 + quad * 8]);
    #pragma unroll
    for (int j = 0; j < 4; j++) b[j] = *(const u16x8*)(&Bs[(wn * 64 + j * 16 + l16) * 40 + quad * 8]);
    #pragma unroll
    for (int i = 0; i < 4; i++)
      #pragma unroll
      for (int j = 0; j < 4; j++)
        acc[i][j] = __builtin_amdgcn_mfma_f32_16x16x32_bf16(
            __builtin_bit_cast(bf16x8, a[i]), __builtin_bit_cast(bf16x8, b[j]),
            acc[i][j], 0, 0, 0);
  }

  if constexpr (DFLAT){
    float other = __shfl_xor(dsum, 1, 64);
    if ((t & 1) == 0){
      int gr = bm0 + (t >> 1);
      if (gr < M) atomicAdd(&dflat[(size_t)bz * 8192 + gr], dsum + other);
    }
  }

  float* Cf = (float*)Cptr + (size_t)(bz * sC);
  u16t*  Ch = (u16t*)Cptr + (size_t)(bz * sC);
  const u16t* addp = (EPI == 3) ? (addsrc + (size_t)(bz * sAdd)) : nullptr;
  #pragma unroll
  for (int i = 0; i < 4; i++){
    int rb = bm0 + wm * 64 + i * 16 + quad * 4;
    #pragma unroll
    for (int j = 0; j < 4; j++){
      int col = bn0 + wn * 64 + j * 16 + l16;
      if (col >= N) continue;
      float bv = bias ? bias[col > biasmax ? biasmax : col] : 0.f;
      #pragma unroll
      for (int rg = 0; rg < 4; rg++){
        int row = rb + rg;
        if (row >= M) continue;
        float v = acc[i][j][rg] + bv;
        if constexpr (EPI == 1){
          v = fmaxf(v, 0.f) * mask[row];
          Ch[(size_t)row * ldc + col] = f2bf(v);
        } else if constexpr (EPI == 2){
          Ch[(size_t)row * ldc + col] = f2bf(v);
        } else if constexpr (EPI == 3){
          v += bf2f(addp[(size_t)row * ldadd + col]);
          Cf[(size_t)row * ldc + col] = v;
        } else if constexpr (EPI == 4){
          atomicAdd(&Cf[(size_t)row * ldc + col], v);
        } else {
          Cf[(size_t)row * ldc + col] = v;
        }
      }
    }
  }
}

// --------------------------------------------------------------------------
// L2-normalize rows of Z [16384][512] -> bf16 into CC[:, 0:512] (ld 768)
__global__ __launch_bounds__(256) void norm_k(const float* __restrict__ Z, u16t* __restrict__ CC){
  __shared__ float red[8];
  int n = blockIdx.x, t = threadIdx.x;
  const float* z = Z + (size_t)n * 512;
  float v0 = z[t], v1 = z[t + 256];
  float tot = blockSum(v0 * v0 + v1 * v1, red);
  float inv = 1.f / (sqrtf(tot) + 1e-12f);
  u16t* o = CC + (size_t)n * 768;
  o[t] = f2bf(v0 * inv);
  o[t + 256] = f2bf(v1 * inv);
}

// softmax over 100 cols (+poolb); write s (bf16) into CC[:,624:724] and s^T into ST
__global__ __launch_bounds__(256) void softmax_k(const float* __restrict__ SR, const float* __restrict__ pb,
                                                 const float* __restrict__ mask,
                                                 u16t* __restrict__ CC, u16t* __restrict__ ST){
  int w = threadIdx.x >> 6, lane = threadIdx.x & 63;
  int n = blockIdx.x * 4 + w;
  const float* r = SR + (size_t)n * 112;
  float v0 = (lane < 100) ? r[lane] + pb[lane] : -1e30f;
  float v1 = (lane + 64 < 100) ? r[lane + 64] + pb[lane + 64] : -1e30f;
  float m = waveMax(fmaxf(v0, v1));
  float e0 = (lane < 100) ? __expf(v0 - m) : 0.f;
  float e1 = (lane + 64 < 100) ? __expf(v1 - m) : 0.f;
  float s = waveSum(e0 + e1);
  float inv = mask[n] / s;
  int b = n >> 13, nn = n & 8191;
  u16t* cc = CC + (size_t)n * 768 + 624;
  if (lane < 100){
    u16t h = f2bf(e0 * inv);
    cc[lane] = h;
    ST[((size_t)b * 112 + lane) * 8192 + nn] = h;
  }
  if (lane + 64 < 100){
    u16t h = f2bf(e1 * inv);
    cc[lane + 64] = h;
    ST[((size_t)b * 112 + lane + 64) * 8192 + nn] = h;
  }
}

// Y3F fp32 [16384][112] -> bf16 CC[:,512:612]
__global__ void cvty3_k(const float* __restrict__ Y, u16t* __restrict__ CC){
  int n = blockIdx.x, t = threadIdx.x;
  if (t < 100) CC[(size_t)n * 768 + 512 + t] = f2bf(Y[(size_t)n * 112 + t]);
}

// mincut_den[b] = sum_n dflat[n] * sum_k s[n,k]^2
__global__ __launch_bounds__(256) void den_k(const u16t* __restrict__ CC, const float* __restrict__ dflat,
                                             float* __restrict__ scal){
  __shared__ float red[8];
  int n = blockIdx.x * 256 + threadIdx.x;
  const u16t* s = CC + (size_t)n * 768 + 624;
  float ssq = 0.f;
  for (int k = 0; k < 100; k++){ float v = bf2f(s[k]); ssq += v * v; }
  float tot = blockSum(dflat[n] * ssq, red);
  if (threadIdx.x == 0) atomicAdd(&scal[n >> 13], tot);
}

__global__ __launch_bounds__(256) void losses_k(const float* __restrict__ OUTB, const float* __restrict__ scal,
                                                float* __restrict__ dout){
  __shared__ float red[8];
  __shared__ float fro[2], orth[2], num[2];
  int t = threadIdx.x;
  for (int b = 0; b < 2; b++){
    const float* base = OUTB + (size_t)b * 112 * 768;
    float p = 0.f;
    for (int idx = t; idx < 10000; idx += 256){
      int k = idx / 100, l = idx - k * 100;
      float v = base[(size_t)k * 768 + 624 + l];
      p += v * v;
    }
    float tot = blockSum(p, red);
    if (t == 0) fro[b] = sqrtf(tot);
    float q = (t < 100) ? base[(size_t)t * 768 + 512 + t] : 0.f;
    float ntot = blockSum(q, red);
    if (t == 0) num[b] = ntot;
  }
  __syncthreads();
  for (int b = 0; b < 2; b++){
    const float* base = OUTB + (size_t)b * 112 * 768;
    float f = fro[b] + EPSF;
    float p = 0.f;
    for (int idx = t; idx < 10000; idx += 256){
      int k = idx / 100, l = idx - k * 100;
      float v = base[(size_t)k * 768 + 624 + l] / f - ((k == l) ? 0.1f : 0.f);
      p += v * v;
    }
    float tot = blockSum(p, red);
    if (t == 0) orth[b] = sqrtf(tot);
  }
  __syncthreads();
  if (t == 0){
    float mc = -0.5f * (num[0] / (scal[0] + EPSF) + num[1] / (scal[1] + EPSF));
    float ol = 0.5f * (orth[0] + orth[1]);
    dout[404] = mc + ol;
  }
}

__global__ __launch_bounds__(256) void outadj_k(const float* __restrict__ OUTB, float* __restrict__ dout){
  __shared__ float T[10000];
  __shared__ float D[100];
  int b = blockIdx.x, t = threadIdx.x;
  const float* base = OUTB + (size_t)b * 112 * 768;
  for (int idx = t; idx < 10000; idx += 256){
    int k = idx / 100, l = idx - k * 100;
    T[idx] = (k == l) ? 0.f : base[(size_t)k * 768 + 512 + l];
  }
  __syncthreads();
  if (t < 100){
    float s = 0.f;
    for (int l = 0; l < 100; l++) s += T[t * 100 + l];
    D[t] = sqrtf(s) + EPSF;
  }
  __syncthreads();
  float* o = dout + 33173 + b * 10000;
  for (int idx = t; idx < 10000; idx += 256){
    int k = idx / 100, l = idx - k * 100;
    o[idx] = T[idx] / (D[k] * D[l]);
  }
}

__global__ __launch_bounds__(256) void attn_k(const float* __restrict__ OUTB, const float* __restrict__ cls,
    const float* __restrict__ aw1, const float* __restrict__ ab1,
    const float* __restrict__ aw2, const float* __restrict__ ab2,
    const float* __restrict__ pw, const float* __restrict__ pb, float* __restrict__ dout){
  __shared__ float xp[512];
  __shared__ float h[512];
  __shared__ float red[8];
  int blk = blockIdx.x;
  int b = blk / 101, r = blk % 101;
  int t = threadIdx.x;
  const float* src = (r == 0) ? cls : (OUTB + ((size_t)b * 112 + (r - 1)) * 768);
  xp[t] = src[t]; xp[t + 256] = src[t + 256];
  __syncthreads();
  #pragma unroll
  for (int ee = 0; ee < 2; ee++){
    int e = t + ee * 256;
    float acc = ab1[e];
    for (int f = 0; f < 512; f++) acc += xp[f] * aw1[(size_t)f * 512 + e];
    h[e] = tanhf(acc);
  }
  __syncthreads();
  float pa = h[t] * aw2[t] + h[t + 256] * aw2[t + 256];
  float alog = blockSum(pa, red);
  float attn = 1.f / (1.f + __expf(-(alog + ab2[0])));
  float p0 = xp[t] * pw[(size_t)t * 2] + xp[t + 256] * pw[(size_t)(t + 256) * 2];
  float l0 = blockSum(p0, red);
  float p1 = xp[t] * pw[(size_t)t * 2 + 1] + xp[t + 256] * pw[(size_t)(t + 256) * 2 + 1];
  float l1 = blockSum(p1, red);
  if (t == 0){
    dout[((size_t)b * 101 + r) * 2 + 0] = attn * (l0 + pb[0]);
    dout[((size_t)b * 101 + r) * 2 + 1] = attn * (l1 + pb[1]);
  }
}

__global__ __launch_bounds__(256) void fusion_k(const float* __restrict__ PL, const float* __restrict__ PR,
    const float* __restrict__ GLW, const float* __restrict__ GLB,
    const float* __restrict__ GRW, const float* __restrict__ GRB,
    const float* __restrict__ LG, const float* __restrict__ LB, float* __restrict__ dout){
  __shared__ float pl[1024], pr[1024], pre[1024];
  __shared__ float red[8];
  int p = blockIdx.x, t = threadIdx.x;
  #pragma unroll
  for (int i = 0; i < 4; i++){
    pl[t + i * 256] = PL[(size_t)p * 1024 + t + i * 256];
    pr[t + i * 256] = PR[(size_t)p * 1024 + t + i * 256];
  }
  __syncthreads();
  #pragma unroll
  for (int i = 0; i < 4; i++){
    int j = t + i * 256;
    float al = GLB[j], ar = GRB[j];
    for (int d = 0; d < 1024; d++){
      al += pl[d] * GLW[(size_t)d * 1024 + j];
      ar += pr[d] * GRW[(size_t)d * 1024 + j];
    }
    float gl = 1.f / (1.f + __expf(-al));
    float gr = 1.f / (1.f + __expf(-ar));
    pre[j] = gl * pl[j] + gr * pr[j];
  }
  __syncthreads();
  float ps = 0.f;
  for (int i = 0; i < 4; i++) ps += pre[t + i * 256];
  float mu = blockSum(ps, red) * (1.f / 1024.f);
  float pv = 0.f;
  for (int i = 0; i < 4; i++){ float d = pre[t + i * 256] - mu; pv += d * d; }
  float var = blockSum(pv, red) * (1.f / 1024.f);
  float rs = rsqrtf(var + 1e-5f);
  float* o = dout + 405 + (size_t)p * 1024;
  for (int i = 0; i < 4; i++){
    int j = t + i * 256;
    o[j] = (pre[j] - mu) * rs * LG[j] + LB[j];
  }
}

// ===========================================================================
extern "C" void kernel_launch(void* const* d_in, const int* in_sizes, int n_in,
                              void* d_out, int out_size, void* d_ws, size_t ws_size,
                              hipStream_t stream)
{
  const float* node_feat = (const float*)d_in[0];
  const float* adj   = (const float*)d_in[1];
  const float* maskp = (const float*)d_in[2];
  const float* fc1w  = (const float*)d_in[3];
  const float* fc1b  = (const float*)d_in[4];
  const float* gcnw  = (const float*)d_in[5];
  const float* gcnb  = (const float*)d_in[6];
  const float* poolw = (const float*)d_in[7];
  const float* poolb = (const float*)d_in[8];
  const float* cls   = (const float*)d_in[9];
  const float* aw1   = (const float*)d_in[10];
  const float* ab1   = (const float*)d_in[11];
  const float* aw2   = (const float*)d_in[12];
  const float* ab2   = (const float*)d_in[13];
  const float* predw = (const float*)d_in[14];
  const float* predb = (const float*)d_in[15];
  const float* glw   = (const float*)d_in[16];
  const float* glb   = (const float*)d_in[17];
  const float* grw   = (const float*)d_in[18];
  const float* grb   = (const float*)d_in[19];
  const float* lng   = (const float*)d_in[20];
  const float* lnb   = (const float*)d_in[21];
  const float* prl   = (const float*)d_in[22];
  const float* prr   = (const float*)d_in[23];
  float* dout = (float*)d_out;

  char* ws = (char*)d_ws;
  size_t off = 0;
  auto take = [&](size_t bytes) -> char* {
    char* p = ws + off;
    off = (off + bytes + 255) & ~(size_t)255;
    return p;
  };
  u16t* FC1WT = (u16t*)take((size_t)512 * 1024 * 2);   // fc1_w^T  [512][1024]
  u16t* GCNWT = (u16t*)take((size_t)512 * 512 * 2);    // gcn_w^T  [512][512]
  u16t* POOLWT= (u16t*)take((size_t)100 * 512 * 2);    // pool_w^T [100][512]
  u16t* X1    = (u16t*)take((size_t)16384 * 512 * 2);  // relu(fc1)*mask
  u16t* W     = (u16t*)take((size_t)16384 * 512 * 2);  // X1 @ gcn_w
  u16t* WT    = (u16t*)take((size_t)2 * 512 * 8192 * 2);  // per-batch W^T
  float* Z    = (float*)take((size_t)16384 * 512 * 4);
  u16t* CC    = (u16t*)take((size_t)2 * 8192 * 768 * 2);  // [X2 | Y3 | s]
  u16t* CCT   = (u16t*)take((size_t)2 * 768 * 8192 * 2);  // per-batch CC^T
  u16t* ST    = (u16t*)take((size_t)2 * 112 * 8192 * 2);  // s^T
  float* OUTB = (float*)take((size_t)2 * 112 * 768 * 4);
  float* Y3F  = (float*)take((size_t)16384 * 112 * 4);
  float* SRAW = (float*)take((size_t)16384 * 112 * 4);
  float* DFLAT= (float*)take((size_t)16384 * 4);
  float* SCAL = (float*)take(256);

  hipMemsetAsync(SCAL, 0, 32, stream);
  hipMemsetAsync(DFLAT, 0, (size_t)16384 * 4, stream);
  hipMemsetAsync(Y3F, 0, (size_t)16384 * 112 * 4, stream);
  hipMemsetAsync(SRAW, 0, (size_t)16384 * 112 * 4, stream);
  hipMemsetAsync(OUTB, 0, (size_t)2 * 112 * 768 * 4, stream);

  // weight transposes (fp32 -> bf16)
  tr_k<true><<<dim3(8, 16, 1), 256, 0, stream>>>(fc1w, FC1WT, 1024, 512, 512, 1024, 0, 0);
  tr_k<true><<<dim3(8, 8, 1), 256, 0, stream>>>(gcnw, GCNWT, 512, 512, 512, 512, 0, 0);
  tr_k<true><<<dim3(2, 8, 1), 256, 0, stream>>>(poolw, POOLWT, 512, 100, 100, 512, 0, 0);

  // X1 = relu(node_feat @ fc1_w + fc1_b) * mask   [16384, 512] bf16
  gemm_k<true, 1, false><<<dim3(4, 128, 1), 256, 0, stream>>>(
      node_feat, FC1WT, X1, 16384, 512, 1024, 1024, 1024, 512,
      0, 0, 0, fc1b, 511, nullptr, 0, 0, maskp, nullptr, 4, 1024);
  // W = X1 @ gcn_w   [16384, 512] bf16
  gemm_k<false, 2, false><<<dim3(4, 128, 1), 256, 0, stream>>>(
      X1, GCNWT, W, 16384, 512, 512, 512, 512, 512,
      0, 0, 0, nullptr, 0, nullptr, 0, 0, nullptr, nullptr, 4, 512);
  // WT per batch
  tr_k<false><<<dim3(8, 128, 2), 256, 0, stream>>>(
      W, WT, 8192, 512, 512, 8192, (long long)8192 * 512, (long long)512 * 8192);
  // Z = adj @ W + W + gcn_b   (per batch)  [16384, 512] fp32
  gemm_k<true, 3, false><<<dim3(4, 64, 2), 256, 0, stream>>>(
      adj, WT, Z, 8192, 512, 8192, 8192, 8192, 512,
      (long long)8192 * 8192, (long long)512 * 8192, (long long)8192 * 512,
      gcnb, 511, W, 512, (long long)8192 * 512, nullptr, nullptr, 4, 8192);
  // X2 = row-normalize(Z) -> CC[:, 0:512]
  norm_k<<<16384, 256, 0, stream>>>(Z, CC);
  // s_raw = X2 @ pool_w  [16384, 100] fp32 (ld 112), split-K x2, atomic
  gemm_k<false, 4, false><<<dim3(2, 128, 1), 256, 0, stream>>>(
      CC, POOLWT, SRAW, 16384, 100, 512, 768, 512, 112,
      0, 0, 0, nullptr, 0, nullptr, 0, 0, nullptr, nullptr, 1, 256);
  // s = softmax(s_raw + poolb) * mask -> CC[:, 624:724] and ST
  softmax_k<<<4096, 256, 0, stream>>>(SRAW, poolb, maskp, CC, ST);
  // Y3 = adj @ s (split-K x4, atomic fp32) + dflat = adj.sum(-1)
  gemm_k<true, 4, true><<<dim3(4, 64, 2), 256, 0, stream>>>(
      adj, ST, Y3F, 8192, 100, 8192, 8192, 8192, 112,
      (long long)8192 * 8192, (long long)112 * 8192, (long long)8192 * 112,
      nullptr, 0, nullptr, 0, 0, nullptr, DFLAT, 1, 2048);
  // Y3 -> bf16 into CC[:,512:612]
  cvty3_k<<<16384, 128, 0, stream>>>(Y3F, CC);
  // CCT per batch
  tr_k<false><<<dim3(12, 128, 2), 256, 0, stream>>>(
      CC, CCT, 8192, 768, 768, 8192, (long long)8192 * 768, (long long)768 * 8192);
  // OUTB = s^T @ [X2 | Y3 | s]  (split-K x16, atomic)
  gemm_k<false, 4, false><<<dim3(96, 1, 2), 256, 0, stream>>>(
      ST, CCT, OUTB, 100, 736, 8192, 8192, 8192, 768,
      (long long)112 * 8192, (long long)768 * 8192, (long long)112 * 768,
      nullptr, 0, nullptr, 0, 0, nullptr, nullptr, 6, 512);

  den_k<<<64, 256, 0, stream>>>(CC, DFLAT, SCAL);
  losses_k<<<1, 256, 0, stream>>>(OUTB, SCAL, dout);
  outadj_k<<<2, 256, 0, stream>>>(OUTB, dout);
  attn_k<<<202, 256, 0, stream>>>(OUTB, cls, aw1, ab1, aw2, ab2, predw, predb, dout);
  fusion_k<<<32, 256, 0, stream>>>(prl, prr, glw, glb, grw, grb, lng, lnb, dout);

  (void)in_sizes; (void)n_in; (void)out_size; (void)ws_size;
}